// Round 15
// baseline (116.431 us; speedup 1.0000x reference)
//
#include <hip/hip_runtime.h>
#include <hip/hip_bf16.h>

typedef __bf16 bf16_t;
typedef bf16_t bf16x4 __attribute__((ext_vector_type(4)));
typedef bf16_t bf16x8 __attribute__((ext_vector_type(8)));
typedef float f32x4 __attribute__((ext_vector_type(4)));

#define MFMA(a, b, c) __builtin_amdgcn_mfma_f32_16x16x32_bf16(a, b, c, 0, 0, 0)

constexpr int B = 8, S = 2048, C = 1024, D = 128;
constexpr float C2 = 0.12751744f; // log2(e)/sqrt(128)

// Frag-major: frag(blk16, kk) = 1KB block; lane = ((k>>3)&3)*16 + (dim&15),
// 8 contiguous k per lane. Serves both A- and B-operands of mfma_16x16x32.

// ---------------- K0: W[c][n] -> Wf frag-major ----------------------------
__global__ __launch_bounds__(256) void k_wt(const float* Wq, const float* Wk, const float* Wv, bf16_t* Wf) {
    int ct = blockIdx.x, w = blockIdx.y; // ct 0..63, w 0..2
    const float* src = (w == 0) ? Wq : ((w == 1) ? Wk : Wv);
    __shared__ bf16_t tile[16][132];
    int t = threadIdx.x;
    int cr = t >> 4, dq = t & 15;
    const float* p = src + (size_t)(ct * 16 + cr) * D + dq * 8;
    f32x4 v0 = *(const f32x4*)p;
    f32x4 v1 = *(const f32x4*)(p + 4);
#pragma unroll
    for (int q = 0; q < 4; ++q) { tile[cr][dq * 8 + q] = (bf16_t)v0[q]; tile[cr][dq * 8 + 4 + q] = (bf16_t)v1[q]; }
    __syncthreads();
    int n = t >> 1, g = t & 1;
    bf16x8 o;
#pragma unroll
    for (int cc = 0; cc < 8; ++cc) o[cc] = tile[g * 8 + cc][n];
    int c8 = ct * 2 + g;
    int nblk = w * 8 + (n >> 4);
    size_t a = ((size_t)(nblk * 32 + (c8 >> 2)) * 64 + (c8 & 3) * 16 + (n & 15)) * 8;
    *(bf16x8*)(Wf + a) = o;
}

// ---------------- K1: fused QKV projection (r13 structure) ----------------
__global__ __launch_bounds__(512, 4) void k_qkv(const float* X, const bf16_t* Wf,
                                                bf16_t* Qf, bf16_t* Kf, float* Vf,
                                                float* Out) {
    __shared__ __align__(16) char pool_[65536]; // 64 KiB union
    bf16_t* xfr = (bf16_t*)pool_;               // main loop: 64 frags x 1KB
    bf16_t* qkL = (bf16_t*)pool_;               // epi: [32 m][264] bf16 (Q|K)
    float*  vL  = (float*)(pool_ + 16896);      // epi: [32 m][132] f32
    int mt = blockIdx.x; // 0..511
    int t = threadIdx.x;
    int lane = t & 63, wid = t >> 6;
    int lr = lane & 15, lg = lane >> 4;
    int rw = mt * 32;

    { // zero Out (k_out2 atomicAdds later), nontemporal
        f32x4* O4 = (f32x4*)Out;
        f32x4 z = {};
        int u = mt * 512 + t;
        __builtin_nontemporal_store(z, O4 + u);
        __builtin_nontemporal_store(z, O4 + u + 262144);
    }

    { // stage whole 32x1024 X-slice frag-major
        f32x4 xa[8], xb[8];
#pragma unroll
        for (int p = 0; p < 8; ++p) {
            int fi = p * 8 + wid;          // rb = fi>>5, kk = fi&31
            int m = rw + (fi >> 5) * 16 + lr;
            int c = (fi & 31) * 32 + lg * 8;
            const f32x4* px = (const f32x4*)(X + (size_t)m * C + c);
            xa[p] = __builtin_nontemporal_load(px);
            xb[p] = __builtin_nontemporal_load(px + 1);
        }
#pragma unroll
        for (int p = 0; p < 8; ++p) {
            bf16x8 o;
#pragma unroll
            for (int q = 0; q < 4; ++q) { o[q] = (bf16_t)xa[p][q]; o[4 + q] = (bf16_t)xb[p][q]; }
            *(bf16x8*)&xfr[(size_t)(p * 8 + wid) * 512 + lane * 8] = o;
        }
    }

    f32x4 acc[2][3] = {};
    const bf16_t* wbase = Wf + (size_t)(wid * 3) * 32 * 512 + lane * 8;
    auto wld = [&](int nf, int kkg) {
        return *(const bf16x8*)(wbase + (size_t)(nf * 32 + kkg) * 512);
    };

    bf16x8 wr_[3][3]; // 3-deep ring
#pragma unroll
    for (int d = 0; d < 3; ++d)
#pragma unroll
        for (int nf = 0; nf < 3; ++nf) wr_[d][nf] = wld(nf, d);
    __syncthreads(); // the ONLY pre-loop barrier

#pragma unroll
    for (int kk = 0; kk < 32; ++kk) {
        int slot = kk % 3;
        bf16x8 a0 = *(const bf16x8*)&xfr[(size_t)kk * 512 + lane * 8];
        bf16x8 a1 = *(const bf16x8*)&xfr[(size_t)(32 + kk) * 512 + lane * 8];
        __builtin_amdgcn_s_setprio(1);
        acc[0][0] = MFMA(a0, wr_[slot][0], acc[0][0]);
        acc[1][0] = MFMA(a1, wr_[slot][0], acc[1][0]);
        acc[0][1] = MFMA(a0, wr_[slot][1], acc[0][1]);
        acc[1][1] = MFMA(a1, wr_[slot][1], acc[1][1]);
        acc[0][2] = MFMA(a0, wr_[slot][2], acc[0][2]);
        acc[1][2] = MFMA(a1, wr_[slot][2], acc[1][2]);
        __builtin_amdgcn_s_setprio(0);
        if (kk < 29) {
#pragma unroll
            for (int nf = 0; nf < 3; ++nf) wr_[slot][nf] = wld(nf, kk + 3);
        }
    }

    // ---- epilogue: acc -> padded LDS image -> coalesced nt stores ----
    __syncthreads();
#pragma unroll
    for (int mi = 0; mi < 2; ++mi)
#pragma unroll
        for (int nf = 0; nf < 3; ++nf) {
            int n = wid * 48 + nf * 16 + lr;
            int sel = (wid * 48 + nf * 16) >> 7; // wave-uniform per nf
#pragma unroll
            for (int r = 0; r < 4; ++r) {
                int mloc = mi * 16 + lg * 4 + r;
                float v = acc[mi][nf][r];
                if (sel == 2) vL[mloc * 132 + (n - 256)] = v;
                else          qkL[mloc * 264 + n] = (bf16_t)v;
            }
        }
    __syncthreads();
#pragma unroll
    for (int p = 0; p < 2; ++p) {
        int F = wid * 2 + p; // 0..15
        int isK = F >> 3, iblk = (F >> 2) & 1, dblk = F & 3;
        int m16 = lane & 15, kg = lane >> 4;
        int col = isK * 128 + dblk * 32 + kg * 8;
        bf16x8 o = *(const bf16x8*)&qkL[(iblk * 16 + m16) * 264 + col];
        bf16_t* dst = isK ? Kf : Qf;
        size_t frg = (size_t)((rw >> 4) + iblk) * 4 + dblk;
        __builtin_nontemporal_store(o, (bf16x8*)(dst + (frg * 64 + lane) * 8));
    }
#pragma unroll
    for (int p = 0; p < 2; ++p) {
        int u = p * 512 + t;          // 0..1023
        int m = u >> 5, dq = u & 31;
        f32x4 v = *(const f32x4*)&vL[m * 132 + dq * 4];
        __builtin_nontemporal_store(v, (f32x4*)(Vf + (size_t)(rw + m) * D + dq * 4));
    }
}

// ---------------- K2: k_sp — swapped QK^T ONCE: col-sums l[j] + P-cache ----
// 512 blocks = 8b x 64jt(32 j); 8 waves = i-octants, 16 steps x 16 i.
// Per step: P^T frags -> exp2 -> ls accumulate + bounce to A-frag -> nt store.
// Tail: V scale/transpose to Vt2 (as before).
__global__ __launch_bounds__(512, 4) void k_sp(const bf16_t* Qf, const bf16_t* Kf,
                                               const float* Vf, bf16_t* Vt2, bf16_t* Pf) {
    int l = blockIdx.x;          // 512 blocks
    int b = l & 7, jt = l >> 3;  // b pinned to XCD; jt 0..63
    int j0 = jt * 32;
    int t = threadIdx.x;
    int lane = t & 63, wid = t >> 6;
    int lr = lane & 15, lg = lane >> 4;
    __shared__ __align__(16) bf16_t vtile[128 * 40];  // 10 KiB
    __shared__ __align__(16) bf16_t pl_all[8][1280];  // 20 KiB, per-wave bounce
    __shared__ float lsum[256];
    __shared__ float linv[32];
    bf16_t* pl = pl_all[wid];

    bf16x8 kf[2][4];
    int jblkg = (b * S + j0) >> 4;
#pragma unroll
    for (int jF = 0; jF < 2; ++jF)
#pragma unroll
        for (int kk = 0; kk < 4; ++kk)
            kf[jF][kk] = *(const bf16x8*)(Kf + ((size_t)((jblkg + jF) * 4 + kk) * 64 + lane) * 8);

    float ls[2][4] = {};
    bf16_t* pbase = Pf + ((size_t)(b * 128 + wid * 16) * 64 + jt) * 512 + lane * 8;

#pragma unroll 4
    for (int tt = 0; tt < 16; ++tt) {
        int iblk = (b * S + wid * 256 + tt * 16) >> 4;
        bf16x8 qa[4];
#pragma unroll
        for (int kk = 0; kk < 4; ++kk)
            qa[kk] = *(const bf16x8*)(Qf + ((size_t)(iblk * 4 + kk) * 64 + lane) * 8);
#pragma unroll
        for (int jF = 0; jF < 2; ++jF) {
            // swapped: lane holds S^T[j = j0 + jF*16 + lg*4 + r][i = base + lr]
            f32x4 s = {};
            s = MFMA(kf[jF][0], qa[0], s);
            s = MFMA(kf[jF][1], qa[1], s);
            s = MFMA(kf[jF][2], qa[2], s);
            s = MFMA(kf[jF][3], qa[3], s);
            bf16x4 pv;
#pragma unroll
            for (int r = 0; r < 4; ++r) {
                float e = exp2f(s[r] * C2);
                ls[jF][r] += e;
                pv[r] = (bf16_t)e;
            }
            *(bf16x4*)&pl[lr * 40 + jF * 16 + lg * 4] = pv;
        }
        // read back as A-frag (row i=lr, j-window lg*8) and nt-store to Pf
        bf16x8 pa = *(const bf16x8*)&pl[lr * 40 + lg * 8];
        __builtin_nontemporal_store(pa, (bf16x8*)(pbase + (size_t)tt * 64 * 512));
    }
    // l[j] reduce: over i = over lr-group (xor 1,2,4,8), then cross-wave
#pragma unroll
    for (int jF = 0; jF < 2; ++jF)
#pragma unroll
        for (int r = 0; r < 4; ++r) {
            float v = ls[jF][r];
            v += __shfl_xor(v, 1); v += __shfl_xor(v, 2);
            v += __shfl_xor(v, 4); v += __shfl_xor(v, 8);
            if (lr == 0) lsum[wid * 32 + jF * 16 + lg * 4 + r] = v;
        }
    __syncthreads();
    if (t < 32) {
        float ss = 0.f;
#pragma unroll
        for (int w = 0; w < 8; ++w) ss += lsum[w * 32 + t];
        linv[t] = 1.0f / ss;
    }
    __syncthreads();
    // scale + transpose V into pad-40 vtile, emit frag-major Vt2
#pragma unroll
    for (int p = 0; p < 2; ++p) {
        int u = p * 512 + t;
        int jj = u & 31, dq = u >> 5;
        f32x4 v = *(const f32x4*)(Vf + (size_t)(b * S + j0 + jj) * D + dq * 4);
        float inv = linv[jj];
#pragma unroll
        for (int q = 0; q < 4; ++q)
            vtile[(dq * 4 + q) * 40 + jj] = (bf16_t)(v[q] * inv);
    }
    __syncthreads();
    {
        int d = t >> 2, jg = t & 3;
        bf16x8 row = *(const bf16x8*)&vtile[d * 40 + jg * 8];
        size_t j32g = (size_t)b * 64 + jt;
        size_t a = ((j32g * 8 + (d >> 4)) * 64 + jg * 16 + (d & 15)) * 8;
        *(bf16x8*)(Vt2 + a) = row;
    }
}

// ---------------- K3: k_out2 — pure PV GEMM: out = P_hat @ Vdiv -----------
// 512 blocks = 8b x 32it(64 i) x 2jh(1024 j); 8 waves = 4 iblk x 2 d-half.
// Per k-step: 1 P A-frag + 4 V B-frags (all coalesced 1KB) + 4 MFMA.
// No LDS, no barriers, no exp2. 2 atomicAdd contributors per element.
__global__ __launch_bounds__(512, 4) void k_out2(const bf16_t* Pf, const bf16_t* Vt2,
                                                 float* Out) {
    int l = blockIdx.x;            // 512 blocks
    int b = l & 7, it = (l >> 3) & 31, jh = l >> 8;
    int t = threadIdx.x;
    int lane = t & 63, wid = t >> 6;
    int lr = lane & 15, lg = lane >> 4;
    int wib = wid >> 1, dh = wid & 1; // wave: iblk = it*4+wib, d-half dh

    f32x4 acc[4] = {};
    const bf16_t* abase = Pf + (((size_t)(b * 128 + it * 4 + wib) * 64) + jh * 32) * 512 + lane * 8;
    const bf16_t* vbase = Vt2 + ((size_t)((b * 64 + jh * 32) * 8 + dh * 4) * 64 + lane) * 8;

#pragma unroll 4
    for (int ks = 0; ks < 32; ++ks) {
        bf16x8 pa = *(const bf16x8*)(abase + (size_t)ks * 512);
        const bf16_t* vp = vbase + (size_t)ks * 8 * 512;
        __builtin_amdgcn_s_setprio(1);
#pragma unroll
        for (int dc = 0; dc < 4; ++dc) {
            bf16x8 vv = *(const bf16x8*)(vp + (size_t)dc * 512);
            acc[dc] = MFMA(pa, vv, acc[dc]);
        }
        __builtin_amdgcn_s_setprio(0);
    }

#pragma unroll
    for (int dc = 0; dc < 4; ++dc)
#pragma unroll
        for (int r = 0; r < 4; ++r)
            atomicAdd(&Out[(size_t)(b * S + (it * 4 + wib) * 16 + lg * 4 + r) * 128 + dh * 64 + dc * 16 + lr],
                      acc[dc][r]);
}

extern "C" void kernel_launch(void* const* d_in, const int* in_sizes, int n_in,
                              void* d_out, int out_size, void* d_ws, size_t ws_size,
                              hipStream_t stream) {
    const float* X  = (const float*)d_in[0];
    const float* Wq = (const float*)d_in[1];
    const float* Wk = (const float*)d_in[2];
    const float* Wv = (const float*)d_in[3];
    char* ws = (char*)d_ws;
    bf16_t* Wf  = (bf16_t*)(ws);                 // 768 KiB (frag-major)
    bf16_t* Qf  = (bf16_t*)(ws + (1ull << 20));  // 4 MiB (frag-major)
    bf16_t* Kf  = (bf16_t*)(ws + (5ull << 20));  // 4 MiB (frag-major)
    float*  Vf  = (float*)(ws + (9ull << 20));   // 8 MiB (row-major fp32)
    bf16_t* Vt2 = (bf16_t*)(ws + (17ull << 20)); // 4 MiB (frag-major)
    bf16_t* Pf  = (bf16_t*)(ws + (32ull << 20)); // 64 MiB (A-frag-major)
    float* Out = (float*)d_out;

    k_wt<<<dim3(64, 3), dim3(256), 0, stream>>>(Wq, Wk, Wv, Wf);
    k_qkv<<<dim3(512), dim3(512), 0, stream>>>(X, Wf, Qf, Kf, Vf, Out);
    k_sp<<<dim3(512), dim3(512), 0, stream>>>(Qf, Kf, Vf, Vt2, Pf);
    k_out2<<<dim3(512), dim3(512), 0, stream>>>(Pf, Vt2, Out);
}

// Round 16
// 88.421 us; speedup vs baseline: 1.3168x; 1.3168x over previous
//
#include <hip/hip_runtime.h>
#include <hip/hip_bf16.h>

typedef __bf16 bf16_t;
typedef bf16_t bf16x4 __attribute__((ext_vector_type(4)));
typedef bf16_t bf16x8 __attribute__((ext_vector_type(8)));
typedef float f32x4 __attribute__((ext_vector_type(4)));

#define MFMA(a, b, c) __builtin_amdgcn_mfma_f32_16x16x32_bf16(a, b, c, 0, 0, 0)

constexpr int B = 8, S = 2048, C = 1024, D = 128;
constexpr float C2 = 0.12751744f; // log2(e)/sqrt(128)

// Frag-major: frag(blk16, kk) = 1KB block; lane = ((k>>3)&3)*16 + (dim&15),
// 8 contiguous k per lane. Serves both A- and B-operands of mfma_16x16x32.

// ---------------- K0: W[c][n] -> Wf frag-major ----------------------------
__global__ __launch_bounds__(256) void k_wt(const float* Wq, const float* Wk, const float* Wv, bf16_t* Wf) {
    int ct = blockIdx.x, w = blockIdx.y; // ct 0..63, w 0..2
    const float* src = (w == 0) ? Wq : ((w == 1) ? Wk : Wv);
    __shared__ bf16_t tile[16][132];
    int t = threadIdx.x;
    int cr = t >> 4, dq = t & 15;
    const float* p = src + (size_t)(ct * 16 + cr) * D + dq * 8;
    f32x4 v0 = *(const f32x4*)p;
    f32x4 v1 = *(const f32x4*)(p + 4);
#pragma unroll
    for (int q = 0; q < 4; ++q) { tile[cr][dq * 8 + q] = (bf16_t)v0[q]; tile[cr][dq * 8 + 4 + q] = (bf16_t)v1[q]; }
    __syncthreads();
    int n = t >> 1, g = t & 1;
    bf16x8 o;
#pragma unroll
    for (int cc = 0; cc < 8; ++cc) o[cc] = tile[g * 8 + cc][n];
    int c8 = ct * 2 + g;
    int nblk = w * 8 + (n >> 4);
    size_t a = ((size_t)(nblk * 32 + (c8 >> 2)) * 64 + (c8 & 3) * 16 + (n & 15)) * 8;
    *(bf16x8*)(Wf + a) = o;
}

// ---------------- K1: fused QKV projection (r13 structure) ----------------
__global__ __launch_bounds__(512, 4) void k_qkv(const float* X, const bf16_t* Wf,
                                                bf16_t* Qf, bf16_t* Kf, float* Vf) {
    __shared__ __align__(16) char pool_[65536]; // 64 KiB union
    bf16_t* xfr = (bf16_t*)pool_;               // main loop: 64 frags x 1KB
    bf16_t* qkL = (bf16_t*)pool_;               // epi: [32 m][264] bf16 (Q|K)
    float*  vL  = (float*)(pool_ + 16896);      // epi: [32 m][132] f32
    int mt = blockIdx.x; // 0..511
    int t = threadIdx.x;
    int lane = t & 63, wid = t >> 6;
    int lr = lane & 15, lg = lane >> 4;
    int rw = mt * 32;

    { // stage whole 32x1024 X-slice frag-major
        f32x4 xa[8], xb[8];
#pragma unroll
        for (int p = 0; p < 8; ++p) {
            int fi = p * 8 + wid;          // rb = fi>>5, kk = fi&31
            int m = rw + (fi >> 5) * 16 + lr;
            int c = (fi & 31) * 32 + lg * 8;
            const f32x4* px = (const f32x4*)(X + (size_t)m * C + c);
            xa[p] = __builtin_nontemporal_load(px);
            xb[p] = __builtin_nontemporal_load(px + 1);
        }
#pragma unroll
        for (int p = 0; p < 8; ++p) {
            bf16x8 o;
#pragma unroll
            for (int q = 0; q < 4; ++q) { o[q] = (bf16_t)xa[p][q]; o[4 + q] = (bf16_t)xb[p][q]; }
            *(bf16x8*)&xfr[(size_t)(p * 8 + wid) * 512 + lane * 8] = o;
        }
    }

    f32x4 acc[2][3] = {};
    const bf16_t* wbase = Wf + (size_t)(wid * 3) * 32 * 512 + lane * 8;
    auto wld = [&](int nf, int kkg) {
        return *(const bf16x8*)(wbase + (size_t)(nf * 32 + kkg) * 512);
    };

    bf16x8 wr_[3][3]; // 3-deep ring
#pragma unroll
    for (int d = 0; d < 3; ++d)
#pragma unroll
        for (int nf = 0; nf < 3; ++nf) wr_[d][nf] = wld(nf, d);
    __syncthreads(); // the ONLY pre-loop barrier

#pragma unroll
    for (int kk = 0; kk < 32; ++kk) {
        int slot = kk % 3;
        bf16x8 a0 = *(const bf16x8*)&xfr[(size_t)kk * 512 + lane * 8];
        bf16x8 a1 = *(const bf16x8*)&xfr[(size_t)(32 + kk) * 512 + lane * 8];
        __builtin_amdgcn_s_setprio(1);
        acc[0][0] = MFMA(a0, wr_[slot][0], acc[0][0]);
        acc[1][0] = MFMA(a1, wr_[slot][0], acc[1][0]);
        acc[0][1] = MFMA(a0, wr_[slot][1], acc[0][1]);
        acc[1][1] = MFMA(a1, wr_[slot][1], acc[1][1]);
        acc[0][2] = MFMA(a0, wr_[slot][2], acc[0][2]);
        acc[1][2] = MFMA(a1, wr_[slot][2], acc[1][2]);
        __builtin_amdgcn_s_setprio(0);
        if (kk < 29) {
#pragma unroll
            for (int nf = 0; nf < 3; ++nf) wr_[slot][nf] = wld(nf, kk + 3);
        }
    }

    // ---- epilogue: acc -> padded LDS image -> coalesced nt stores ----
    __syncthreads();
#pragma unroll
    for (int mi = 0; mi < 2; ++mi)
#pragma unroll
        for (int nf = 0; nf < 3; ++nf) {
            int n = wid * 48 + nf * 16 + lr;
            int sel = (wid * 48 + nf * 16) >> 7; // wave-uniform per nf
#pragma unroll
            for (int r = 0; r < 4; ++r) {
                int mloc = mi * 16 + lg * 4 + r;
                float v = acc[mi][nf][r];
                if (sel == 2) vL[mloc * 132 + (n - 256)] = v;
                else          qkL[mloc * 264 + n] = (bf16_t)v;
            }
        }
    __syncthreads();
#pragma unroll
    for (int p = 0; p < 2; ++p) {
        int F = wid * 2 + p; // 0..15
        int isK = F >> 3, iblk = (F >> 2) & 1, dblk = F & 3;
        int m16 = lane & 15, kg = lane >> 4;
        int col = isK * 128 + dblk * 32 + kg * 8;
        bf16x8 o = *(const bf16x8*)&qkL[(iblk * 16 + m16) * 264 + col];
        bf16_t* dst = isK ? Kf : Qf;
        size_t frg = (size_t)((rw >> 4) + iblk) * 4 + dblk;
        __builtin_nontemporal_store(o, (bf16x8*)(dst + (frg * 64 + lane) * 8));
    }
#pragma unroll
    for (int p = 0; p < 2; ++p) {
        int u = p * 512 + t;          // 0..1023
        int m = u >> 5, dq = u & 31;
        f32x4 v = *(const f32x4*)&vL[m * 132 + dq * 4];
        __builtin_nontemporal_store(v, (f32x4*)(Vf + (size_t)(rw + m) * D + dq * 4));
    }
}

// ---------------- K2: column sums l[j] (32 j/block), barrier-free sweep ----
__global__ __launch_bounds__(512, 4) void k_sum(const bf16_t* Qf, const bf16_t* Kf,
                                                const float* Vf, bf16_t* Vt2) {
    int l = blockIdx.x;          // 512 blocks
    int b = l & 7, jt = l >> 3;  // b pinned to XCD; jt 0..63
    int j0 = jt * 32;
    int t = threadIdx.x;
    int lane = t & 63, wid = t >> 6;
    __shared__ __align__(16) bf16_t vtile[128 * 40]; // 10 KiB
    __shared__ float lsum[256];
    __shared__ float linv[32];

    bf16x8 kf[2][4];
    int jblkg = (b * S + j0) >> 4;
#pragma unroll
    for (int jF = 0; jF < 2; ++jF)
#pragma unroll
        for (int kk = 0; kk < 4; ++kk)
            kf[jF][kk] = *(const bf16x8*)(Kf + ((size_t)((jblkg + jF) * 4 + kk) * 64 + lane) * 8);

    float ls0 = 0.f, ls1 = 0.f;
#pragma unroll 4
    for (int tt = 0; tt < 16; ++tt) {
        int iblk = (b * S + wid * 256 + tt * 16) >> 4;
        bf16x8 qa[4];
#pragma unroll
        for (int kk = 0; kk < 4; ++kk)
            qa[kk] = *(const bf16x8*)(Qf + ((size_t)(iblk * 4 + kk) * 64 + lane) * 8);
        f32x4 s0 = {}, s1 = {};
#pragma unroll
        for (int kk = 0; kk < 4; ++kk) {
            s0 = MFMA(qa[kk], kf[0][kk], s0);
            s1 = MFMA(qa[kk], kf[1][kk], s1);
        }
#pragma unroll
        for (int r = 0; r < 4; ++r) { ls0 += exp2f(s0[r] * C2); ls1 += exp2f(s1[r] * C2); }
    }
    {
        float v0 = ls0 + __shfl_xor(ls0, 16); v0 += __shfl_xor(v0, 32);
        float v1 = ls1 + __shfl_xor(ls1, 16); v1 += __shfl_xor(v1, 32);
        if (lane < 16) { lsum[wid * 32 + lane] = v0; lsum[wid * 32 + 16 + lane] = v1; }
    }
    __syncthreads();
    if (t < 32) {
        float ss = 0.f;
#pragma unroll
        for (int w = 0; w < 8; ++w) ss += lsum[w * 32 + t];
        linv[t] = 1.0f / ss;
    }
    __syncthreads();
#pragma unroll
    for (int p = 0; p < 2; ++p) {
        int u = p * 512 + t;
        int jj = u & 31, dq = u >> 5;
        f32x4 v = *(const f32x4*)(Vf + (size_t)(b * S + j0 + jj) * D + dq * 4);
        float inv = linv[jj];
#pragma unroll
        for (int q = 0; q < 4; ++q)
            vtile[(dq * 4 + q) * 40 + jj] = (bf16_t)(v[q] * inv);
    }
    __syncthreads();
    {
        int d = t >> 2, jg = t & 3;
        bf16x8 row = *(const bf16x8*)&vtile[d * 40 + jg * 8];
        size_t j32g = (size_t)b * 64 + jt;
        size_t a = ((j32g * 8 + (d >> 4)) * 64 + jg * 16 + (d & 15)) * 8;
        *(bf16x8*)(Vt2 + a) = row;
    }
}

// ---------------- K3: k_att — wave-independent j-quarter sweeps -----------
// 256 blocks (1/CU) = 8b x 32g; 8 waves = 2 i-units(32 i) x 4 jq(512 j).
// Per wave: Q resident, K/V frag-streams from L2, per-wave pl bounce,
// ZERO barriers in main loop. End: LDS tree-reduce over jq, plain nt stores.
__global__ __launch_bounds__(512, 2) void k_att(const bf16_t* Qf, const bf16_t* Kf,
                                                const bf16_t* Vt2, float* Out) {
    int l = blockIdx.x;           // 256 blocks
    int b = l & 7, g = l >> 3;    // g 0..31
    int t = threadIdx.x;
    int lane = t & 63, wid = t >> 6;
    int lr = lane & 15, lg = lane >> 4;
    int iun = wid >> 2, jq = wid & 3;
    int iu = g * 2 + iun;         // i-unit 0..63 per b (32 i each)
    __shared__ __align__(16) char pool_[33792];  // 33 KiB union
    bf16_t* pl = (bf16_t*)pool_ + wid * 1280;    // [32 i][stride 40] per wave
    float* Ru = (float*)pool_ + iun * 4224;      // reduce: [32 i][132] f32 per i-unit

    bf16x8 qa[2][4];
    int iblkg = (b * S + iu * 32) >> 4;
#pragma unroll
    for (int ib = 0; ib < 2; ++ib)
#pragma unroll
        for (int kk = 0; kk < 4; ++kk)
            qa[ib][kk] = *(const bf16x8*)(Qf + ((size_t)((iblkg + ib) * 4 + kk) * 64 + lane) * 8);

    f32x4 acc[2][8] = {};
    int jb0 = b * 128 + jq * 32;  // 16-j block base
    int jv0 = b * 64 + jq * 16;   // 32-j block base (Vt2)

#pragma unroll 2
    for (int tt = 0; tt < 16; ++tt) {
#pragma unroll
        for (int jF = 0; jF < 2; ++jF) {
            bf16x8 kf[4];
#pragma unroll
            for (int kk = 0; kk < 4; ++kk)
                kf[kk] = *(const bf16x8*)(Kf + ((size_t)((jb0 + tt * 2 + jF) * 4 + kk) * 64 + lane) * 8);
#pragma unroll
            for (int ib = 0; ib < 2; ++ib) {
                // swapped QK^T: lane holds S^T[j = jF*16 + lg*4 + r][i = lr]
                f32x4 s = {};
                s = MFMA(kf[0], qa[ib][0], s);
                s = MFMA(kf[1], qa[ib][1], s);
                s = MFMA(kf[2], qa[ib][2], s);
                s = MFMA(kf[3], qa[ib][3], s);
                bf16x4 pv;
#pragma unroll
                for (int r = 0; r < 4; ++r) pv[r] = (bf16_t)exp2f(s[r] * C2);
                *(bf16x4*)&pl[(ib * 16 + lr) * 40 + jF * 16 + lg * 4] = pv;
            }
        }
        bf16x8 pa0 = *(const bf16x8*)&pl[lr * 40 + lg * 8];
        bf16x8 pa1 = *(const bf16x8*)&pl[(16 + lr) * 40 + lg * 8];
        const bf16_t* vp = Vt2 + ((size_t)(jv0 + tt) * 8 * 64) * 8 + (size_t)lane * 8;
        __builtin_amdgcn_s_setprio(1);
#pragma unroll
        for (int dc = 0; dc < 8; ++dc) {
            bf16x8 vv = *(const bf16x8*)(vp + (size_t)dc * 512);
            acc[0][dc] = MFMA(pa0, vv, acc[0][dc]);
            acc[1][dc] = MFMA(pa1, vv, acc[1][dc]);
        }
        __builtin_amdgcn_s_setprio(0);
    }

    // ---- cross-jq reduce (once per kernel), then plain nt stores ----
    auto wrR = [&]() {
#pragma unroll
        for (int ib = 0; ib < 2; ++ib)
#pragma unroll
            for (int dc = 0; dc < 8; ++dc)
#pragma unroll
                for (int r = 0; r < 4; ++r)
                    Ru[(ib * 16 + lg * 4 + r) * 132 + dc * 16 + lr] = acc[ib][dc][r];
    };
    auto adR = [&]() {
#pragma unroll
        for (int ib = 0; ib < 2; ++ib)
#pragma unroll
            for (int dc = 0; dc < 8; ++dc)
#pragma unroll
                for (int r = 0; r < 4; ++r)
                    acc[ib][dc][r] += Ru[(ib * 16 + lg * 4 + r) * 132 + dc * 16 + lr];
    };
    __syncthreads();
    if (jq == 1) wrR();
    __syncthreads();
    if (jq == 0) adR();
    __syncthreads();
    if (jq == 3) wrR();
    __syncthreads();
    if (jq == 2) adR();
    __syncthreads();
    if (jq == 2) wrR();
    __syncthreads();
    if (jq == 0) {
        adR();
#pragma unroll
        for (int ib = 0; ib < 2; ++ib)
#pragma unroll
            for (int dc = 0; dc < 8; ++dc)
#pragma unroll
                for (int r = 0; r < 4; ++r)
                    __builtin_nontemporal_store(acc[ib][dc][r],
                        &Out[(size_t)(b * S + iu * 32 + ib * 16 + lg * 4 + r) * 128 + dc * 16 + lr]);
    }
}

extern "C" void kernel_launch(void* const* d_in, const int* in_sizes, int n_in,
                              void* d_out, int out_size, void* d_ws, size_t ws_size,
                              hipStream_t stream) {
    const float* X  = (const float*)d_in[0];
    const float* Wq = (const float*)d_in[1];
    const float* Wk = (const float*)d_in[2];
    const float* Wv = (const float*)d_in[3];
    char* ws = (char*)d_ws;
    bf16_t* Wf  = (bf16_t*)(ws);                 // 768 KiB (frag-major)
    bf16_t* Qf  = (bf16_t*)(ws + (1ull << 20));  // 4 MiB (frag-major)
    bf16_t* Kf  = (bf16_t*)(ws + (5ull << 20));  // 4 MiB (frag-major)
    float*  Vf  = (float*)(ws + (9ull << 20));   // 8 MiB (row-major fp32)
    bf16_t* Vt2 = (bf16_t*)(ws + (17ull << 20)); // 4 MiB (frag-major)
    float* Out = (float*)d_out;

    k_wt<<<dim3(64, 3), dim3(256), 0, stream>>>(Wq, Wk, Wv, Wf);
    k_qkv<<<dim3(512), dim3(512), 0, stream>>>(X, Wf, Qf, Kf, Vf);
    k_sum<<<dim3(512), dim3(512), 0, stream>>>(Qf, Kf, Vf, Vt2);
    k_att<<<dim3(256), dim3(512), 0, stream>>>(Qf, Kf, Vt2, Out);
}